// Round 3
// baseline (480.614 us; speedup 1.0000x reference)
//
#include <hip/hip_runtime.h>
#include <math.h>

#define N_IMG 256
#define DIN   768
#define DH    768
#define DOUT  512
#define M_GAL 100000
#define CAP   2048
#define MT    1568  // m-tiles of 64 gallery rows (1568*64 = 100352 >= 100000)

typedef __bf16 bf16_t;
typedef __bf16 bf16x8 __attribute__((ext_vector_type(8)));
typedef float  f32x4  __attribute__((ext_vector_type(4)));
typedef float  f32x16 __attribute__((ext_vector_type(16)));

// ---- workspace layout (float units) ----
#define OFF_H      0                               // 256*768
#define OFF_IMG    (N_IMG*DH)                      // 256*512 pre-norm
#define OFF_IMGN   (OFF_IMG  + N_IMG*DOUT)         // 256*512 f32 normalized
#define OFF_IMGT   (OFF_IMGN + N_IMG*DOUT)         // 256*512 bf16, [k/8][n][8] layout
#define OFF_STATS  (OFF_IMGT + N_IMG*DOUT/2)       // [0]=sumexp [1]=maxkey [2]=counter
#define OFF_CIDX   (OFF_STATS + 4)
#define OFF_CVAL   (OFF_CIDX + CAP)

#define OUT_GPS  ((size_t)N_IMG * (size_t)M_GAL)
#define OUT_PROB (OUT_GPS + 10)

__device__ inline unsigned fkey(float x) {
  unsigned u = __float_as_uint(x);
  return (u & 0x80000000u) ? ~u : (u | 0x80000000u);
}
__device__ inline float fkey_inv(unsigned k) {
  unsigned u = (k & 0x80000000u) ? (k ^ 0x80000000u) : ~k;
  return __uint_as_float(u);
}

// ---------------- MLP GEMM (f32 VALU, 32x32 tile, 2x2 micro) ----------------
template<int KDIM, int NCOLS, bool RELU>
__global__ __launch_bounds__(256) void mlp_gemm(const float* __restrict__ A,
    const float* __restrict__ B, const float* __restrict__ bias,
    float* __restrict__ C, unsigned* stats_init) {
  if (stats_init && blockIdx.x == 0 && blockIdx.y == 0 && threadIdx.x == 0) {
    stats_init[0] = 0u; stats_init[1] = 0u; stats_init[2] = 0u;  // sumexp,maxkey,counter
  }
  __shared__ float As[32][34];
  __shared__ float Bs[32][34];
  const int t  = threadIdx.x;
  const int rowbase = blockIdx.y * 32;
  const int colbase = blockIdx.x * 32;
  const int sm = t >> 3;
  const int kc = (t & 7) << 2;
  const int ty = t >> 4, tx = t & 15;
  float a00 = 0.f, a01 = 0.f, a10 = 0.f, a11 = 0.f;
  for (int kt = 0; kt < KDIM; kt += 32) {
    float4 av = *(const float4*)(A + (size_t)(rowbase + sm) * KDIM + kt + kc);
    float4 bv = *(const float4*)(B + (size_t)(colbase + sm) * KDIM + kt + kc);
    __syncthreads();
    As[kc+0][sm] = av.x; As[kc+1][sm] = av.y; As[kc+2][sm] = av.z; As[kc+3][sm] = av.w;
    Bs[kc+0][sm] = bv.x; Bs[kc+1][sm] = bv.y; Bs[kc+2][sm] = bv.z; Bs[kc+3][sm] = bv.w;
    __syncthreads();
#pragma unroll
    for (int j = 0; j < 32; ++j) {
      float2 a = *(const float2*)(&As[j][2*ty]);
      float2 b = *(const float2*)(&Bs[j][2*tx]);
      a00 = fmaf(a.x, b.x, a00); a01 = fmaf(a.x, b.y, a01);
      a10 = fmaf(a.y, b.x, a10); a11 = fmaf(a.y, b.y, a11);
    }
  }
  const int r0 = rowbase + 2*ty;
  const int c0 = colbase + 2*tx;
  const float bb0 = bias[c0], bb1 = bias[c0+1];
  float v00 = a00 + bb0, v01 = a01 + bb1, v10 = a10 + bb0, v11 = a11 + bb1;
  if (RELU) {
    v00 = fmaxf(v00, 0.f); v01 = fmaxf(v01, 0.f);
    v10 = fmaxf(v10, 0.f); v11 = fmaxf(v11, 0.f);
  }
  C[(size_t)r0*NCOLS + c0]       = v00; C[(size_t)r0*NCOLS + c0 + 1]     = v01;
  C[(size_t)(r0+1)*NCOLS + c0]   = v10; C[(size_t)(r0+1)*NCOLS + c0 + 1] = v11;
}

// ---------------- normalize rows + bf16 cast into [k/8][n][8] layout ----------------
__global__ __launch_bounds__(256) void norm_cast_kernel(const float* __restrict__ img,
    float* __restrict__ img_n, bf16_t* __restrict__ img_t) {
  const int row = blockIdx.x, t = threadIdx.x;
  const float v0 = img[row*DOUT + t];
  const float v1 = img[row*DOUT + 256 + t];
  float s = v0*v0 + v1*v1;
  for (int o = 32; o > 0; o >>= 1) s += __shfl_down(s, o);
  __shared__ float ws4[4];
  if ((t & 63) == 0) ws4[t >> 6] = s;
  __syncthreads();
  const float tot = ws4[0] + ws4[1] + ws4[2] + ws4[3];
  const float inv = 1.0f / sqrtf(tot);
  const float n0 = v0 * inv, n1 = v1 * inv;
  img_n[row*DOUT + t]       = n0;
  img_n[row*DOUT + 256 + t] = n1;
  // transposed bf16 layout: element (n, k) -> img_t[((k>>3)*N_IMG + n)*8 + (k&7)]
  const int k0 = t, k1 = t + 256;
  img_t[(((k0 >> 3)*N_IMG) + row)*8 + (k0 & 7)] = (bf16_t)n0;
  img_t[(((k1 >> 3)*N_IMG) + row)*8 + (k1 & 7)] = (bf16_t)n1;
}

// ---------------- main logits GEMM ----------------
// Block: ALL 256 images x 64 gallery rows (loc single-pass).
// 4 waves; wave = 128 img x 32 gal, mfma_f32_32x32x16_bf16 (acc = 4x f32x16).
// A double-buffered in LDS (2 x 32 KB chunks of 64 K-elems x 256 img):
// STAGE(c+1) is issued at the TOP of chunk c's compute, so the stage overlaps
// the whole compute phase; ONE __syncthreads() per chunk (round 1 had two).
// Sync structure is plain __syncthreads() only (known-good; no hand vmcnt).
// B streamed f32 from loc into regs, depth-3 rotating prefetch (4 slots).
__global__ __launch_bounds__(256, 2) void logits_kernel(const float* __restrict__ loc,
    const bf16_t* __restrict__ img_t, const float* __restrict__ ls,
    float* __restrict__ out, float* __restrict__ sumexp, unsigned* __restrict__ maxkey) {
  __shared__ bf16_t Asl[2 * 8 * 256 * 8];   // 64 KB: [buf][k8 0..7][img 0..255][8]
  const int t = threadIdx.x;
  const int w = t >> 6, l = t & 63;
  const int wr = w >> 1;        // img half: 0 -> imgs 0..127, 1 -> 128..255
  const int wc = w & 1;         // gal half: 0 -> gals +0..31, 1 -> +32..63
  const int hi = l >> 5;        // k-subgroup within K=16 (0: k0..7, 1: k8..15)
  const int lo = l & 31;
  const int mb = blockIdx.x * 64;
  const int m  = mb + wc * 32 + lo;              // this lane's gallery row
  const int mc = m < M_GAL ? m : (M_GAL - 1);    // clamped for loads
  const float* bp = loc + (size_t)mc * 512 + hi * 8;

  f32x16 acc[4];
#pragma unroll
  for (int i = 0; i < 4; ++i) acc[i] = (f32x16)(0.f);

  float4 B0[4], B1[4];   // rotating depth-3 prefetch slots (8 f32 = one bf16x8 B-frag)

#define ISSUE(kt) {                                                   \
    const int s_ = (kt) & 3;                                          \
    const float* p_ = bp + (kt) * 16;                                 \
    B0[s_] = *(const float4*)p_;                                      \
    B1[s_] = *(const float4*)(p_ + 4);                                \
  }

#define COMPUTE(kt, pb) {                                             \
    const int s_  = (kt) & 3;                                         \
    const int kl_ = ((kt) & 3) * 2 + hi;  /* k8 within chunk */       \
    bf16x8 af_[4];                                                    \
    _Pragma("unroll")                                                 \
    for (int i_ = 0; i_ < 4; ++i_)                                    \
      af_[i_] = *(const bf16x8*)(Asl + ((pb) * 2048 + kl_ * 256 + wr * 128 + i_ * 32 + lo) * 8); \
    bf16x8 bf_;                                                       \
    bf_[0] = (bf16_t)B0[s_].x; bf_[1] = (bf16_t)B0[s_].y;             \
    bf_[2] = (bf16_t)B0[s_].z; bf_[3] = (bf16_t)B0[s_].w;             \
    bf_[4] = (bf16_t)B1[s_].x; bf_[5] = (bf16_t)B1[s_].y;             \
    bf_[6] = (bf16_t)B1[s_].z; bf_[7] = (bf16_t)B1[s_].w;             \
    _Pragma("unroll")                                                 \
    for (int i_ = 0; i_ < 4; ++i_)                                    \
      acc[i_] = __builtin_amdgcn_mfma_f32_32x32x16_bf16(af_[i_], bf_, acc[i_], 0, 0, 0); \
  }

  // stage chunk c into buffer pb: 8 rounds x (256 threads x 16 B) = 32 KB
#define STAGE(c_, pb) {                                               \
    _Pragma("unroll")                                                 \
    for (int r_ = 0; r_ < 8; ++r_) {                                  \
      __builtin_amdgcn_global_load_lds(                               \
          (__attribute__((address_space(1))) void*)(img_t + (((c_) * 8 + r_) * 256 + t) * 8), \
          (__attribute__((address_space(3))) void*)(Asl + ((pb) * 2048 + r_ * 256 + t) * 8), \
          16, 0, 0);                                                  \
    } }

  // ---- prologue: stage chunk 0, start B prefetch pipeline, drain once ----
  STAGE(0, 0);
  ISSUE(0); ISSUE(1); ISSUE(2);
  __syncthreads();   // chunk 0 resident (B prefetches also drain here, once)

#pragma unroll
  for (int c = 0; c < 8; ++c) {
    const int pb = c & 1;
    if (c < 7) { STAGE(c + 1, pb ^ 1); }   // overlaps with this chunk's compute
#pragma unroll
    for (int q = 0; q < 4; ++q) {
      const int kt = c * 4 + q;
      if (kt + 3 < 32) { ISSUE(kt + 3); }
      COMPUTE(kt, pb);
    }
    if (c < 7) __syncthreads();   // chunk c+1 resident; waves aligned
  }
#undef ISSUE
#undef COMPUTE
#undef STAGE

  const float scale = expf(ls[0]);
  // ---- row-0 softmax stats folded into epilogue (img 0: wr==0, acc[0] reg 0, hi==0) ----
  if (wr == 0) {
    float mx = -1e30f, se = 0.f;
    if (hi == 0 && m < M_GAL) {
      const float v = scale * acc[0][0];
      mx = v;
      se = expf(v);
    }
#pragma unroll
    for (int o = 1; o < 64; o <<= 1) {
      mx = fmaxf(mx, __shfl_xor(mx, o));
      se += __shfl_xor(se, o);
    }
    if (l == 0) { atomicAdd(sumexp, se); atomicMax(maxkey, fkey(mx)); }
  }
  // ---- store: D col = gallery = lo, row = img = wr*128 + i*32 + (r&3) + 8*(r>>2) + 4*hi ----
  if (m < M_GAL) {
#pragma unroll
    for (int i = 0; i < 4; ++i) {
      const int ib = wr * 128 + i * 32 + hi * 4;
#pragma unroll
      for (int r = 0; r < 16; ++r) {
        const int img = ib + (r & 3) + 8 * (r >> 2);
        out[(size_t)img * M_GAL + m] = scale * acc[i][r];
      }
    }
  }
}

// ---------------- collect candidates within 0.8 of row-0 max ----------------
__global__ __launch_bounds__(256) void collect_kernel(const float* __restrict__ out,
    const unsigned* __restrict__ maxkey, unsigned* __restrict__ counter,
    int* __restrict__ cidx) {
  const int i = blockIdx.x * 256 + threadIdx.x;
  if (i >= M_GAL) return;
  const float thresh = fkey_inv(*maxkey) - 0.8f;
  if (out[i] > thresh) {
    const unsigned p = atomicAdd(counter, 1u);
    if (p < CAP) cidx[p] = i;
  }
}

// ---------------- exact f32 recompute of candidate logits (multi-block) ----------------
__global__ __launch_bounds__(256) void recompute_kernel(const float* __restrict__ loc,
    const float* __restrict__ img_n, const float* __restrict__ ls,
    const unsigned* __restrict__ counter, const int* __restrict__ cidx,
    float* __restrict__ cval) {
  const int w = threadIdx.x >> 6, l = threadIdx.x & 63;
  const unsigned cnt = *counter;
  const int n = (int)(cnt < CAP ? cnt : CAP);
  const float scale = expf(ls[0]);
  for (int c = blockIdx.x * 4 + w; c < n; c += gridDim.x * 4) {
    const int idx = cidx[c];
    const float* B = loc + (size_t)idx * 512;
    float s = 0.f;
#pragma unroll
    for (int e = 0; e < 8; ++e) s = fmaf(img_n[l + e*64], B[l + e*64], s);
    for (int o = 32; o > 0; o >>= 1) s += __shfl_down(s, o);
    if (l == 0) cval[c] = scale * s;
  }
}

// ---------------- exact top-5 among candidates + outputs ----------------
__global__ __launch_bounds__(256) void finalize_kernel(const unsigned* __restrict__ counter,
    const int* __restrict__ cidx, const float* __restrict__ cval,
    const float* __restrict__ gps, const float* __restrict__ sumexp,
    float* __restrict__ out) {
  __shared__ float v[CAP];
  __shared__ int   id[CAP];
  __shared__ float rv[256];
  __shared__ int   ri[256];
  __shared__ int   rs[256];
  const int t = threadIdx.x;
  const unsigned cnt = *counter;
  const int n = (int)(cnt < CAP ? cnt : CAP);
  for (int i = t; i < CAP; i += 256) {
    v[i]  = (i < n) ? cval[i] : -1e30f;
    id[i] = (i < n) ? cidx[i] : 0x7fffffff;
  }
  const float se = *sumexp;
  __syncthreads();
  for (int k = 0; k < 5; ++k) {
    float bv = -1e30f; int bidx = 0x7fffffff; int bslot = -1;
    for (int i = t; i < CAP; i += 256) {
      const float vi = v[i]; const int ii = id[i];
      if (vi > bv || (vi == bv && ii < bidx)) { bv = vi; bidx = ii; bslot = i; }
    }
    rv[t] = bv; ri[t] = bidx; rs[t] = bslot;
    __syncthreads();
    for (int s = 128; s > 0; s >>= 1) {
      if (t < s) {
        if (rv[t+s] > rv[t] || (rv[t+s] == rv[t] && ri[t+s] < ri[t])) {
          rv[t] = rv[t+s]; ri[t] = ri[t+s]; rs[t] = rs[t+s];
        }
      }
      __syncthreads();
    }
    if (t == 0) {
      const int sl = rs[0]; const int gi = ri[0]; const float lv = rv[0];
      float g0 = 0.f, g1 = 0.f, pr = 0.f;
      if (sl >= 0 && gi != 0x7fffffff) {
        g0 = gps[(size_t)gi*2]; g1 = gps[(size_t)gi*2 + 1];
        pr = expf(lv) / se;
        v[sl] = -1e30f; id[sl] = 0x7fffffff;
      }
      out[OUT_GPS + 2*k]     = g0;
      out[OUT_GPS + 2*k + 1] = g1;
      out[OUT_PROB + k]      = pr;
    }
    __syncthreads();
  }
}

extern "C" void kernel_launch(void* const* d_in, const int* in_sizes, int n_in,
                              void* d_out, int out_size, void* d_ws, size_t ws_size,
                              hipStream_t stream) {
  const float* img_feats = (const float*)d_in[0];
  const float* w1  = (const float*)d_in[1];
  const float* b1  = (const float*)d_in[2];
  const float* w2  = (const float*)d_in[3];
  const float* b2  = (const float*)d_in[4];
  const float* ls  = (const float*)d_in[5];
  const float* loc = (const float*)d_in[6];
  const float* gps = (const float*)d_in[7];
  float* out = (float*)d_out;
  float* ws  = (float*)d_ws;

  float*    h       = ws + OFF_H;
  float*    img     = ws + OFF_IMG;
  float*    img_n   = ws + OFF_IMGN;
  bf16_t*   img_t   = (bf16_t*)(ws + OFF_IMGT);
  float*    sumexp  = ws + OFF_STATS;
  unsigned* maxkey  = (unsigned*)(ws + OFF_STATS + 1);
  unsigned* counter = (unsigned*)(ws + OFF_STATS + 2);
  int*      cidx    = (int*)(ws + OFF_CIDX);
  float*    cval    = ws + OFF_CVAL;

  // 1-2: MLP head (f32 exact); first launch also zeroes the stats words
  mlp_gemm<DIN, DH, true><<<dim3(DH/32, N_IMG/32), 256, 0, stream>>>(
      img_feats, w1, b1, h, (unsigned*)(ws + OFF_STATS));
  mlp_gemm<DH, DOUT, false><<<dim3(DOUT/32, N_IMG/32), 256, 0, stream>>>(
      h, w2, b2, img, nullptr);
  // 3: normalize + bf16 transpose-cast
  norm_cast_kernel<<<N_IMG, 256, 0, stream>>>(img, img_n, img_t);
  // 4: streaming logits GEMM (+ row-0 stats folded into epilogue)
  logits_kernel<<<MT, 256, 0, stream>>>(loc, img_t, ls, out, sumexp, maxkey);
  // 5: candidate collection (row 0 only: 400 KB)
  collect_kernel<<<(M_GAL + 255) / 256, 256, 0, stream>>>(out, maxkey, counter, cidx);
  // 6-7: exact f32 recompute (multi-block) + top-5 + gps/prob outputs
  recompute_kernel<<<128, 256, 0, stream>>>(loc, img_n, ls, counter, cidx, cval);
  finalize_kernel<<<1, 256, 0, stream>>>(counter, cidx, cval, gps, sumexp, out);
}

// Round 4
// 442.082 us; speedup vs baseline: 1.0872x; 1.0872x over previous
//
#include <hip/hip_runtime.h>
#include <math.h>

#define N_IMG 256
#define DIN   768
#define DH    768
#define DOUT  512
#define M_GAL 100000
#define CAP   2048
#define MT    1568  // m-tiles of 64 gallery rows (1568*64 = 100352 >= 100000)

typedef __bf16 bf16_t;
typedef __bf16 bf16x8 __attribute__((ext_vector_type(8)));
typedef float  f32x4  __attribute__((ext_vector_type(4)));
typedef float  f32x16 __attribute__((ext_vector_type(16)));

// ---- workspace layout (float units) ----
#define OFF_H      0                               // 256*768
#define OFF_IMG    (N_IMG*DH)                      // 256*512 pre-norm
#define OFF_IMGN   (OFF_IMG  + N_IMG*DOUT)         // 256*512 f32 normalized
#define OFF_IMGT   (OFF_IMGN + N_IMG*DOUT)         // 256*512 bf16, [k/8][n][8] layout
#define OFF_STATS  (OFF_IMGT + N_IMG*DOUT/2)       // [0]=sumexp [1]=maxkey [2]=counter
#define OFF_CIDX   (OFF_STATS + 4)
#define OFF_CVAL   (OFF_CIDX + CAP)

#define OUT_GPS  ((size_t)N_IMG * (size_t)M_GAL)
#define OUT_PROB (OUT_GPS + 10)

__device__ inline unsigned fkey(float x) {
  unsigned u = __float_as_uint(x);
  return (u & 0x80000000u) ? ~u : (u | 0x80000000u);
}
__device__ inline float fkey_inv(unsigned k) {
  unsigned u = (k & 0x80000000u) ? (k ^ 0x80000000u) : ~k;
  return __uint_as_float(u);
}

// ---------------- MLP GEMM (f32 VALU, 32x32 tile, 2x2 micro) ----------------
template<int KDIM, int NCOLS, bool RELU>
__global__ __launch_bounds__(256) void mlp_gemm(const float* __restrict__ A,
    const float* __restrict__ B, const float* __restrict__ bias,
    float* __restrict__ C, unsigned* stats_init) {
  if (stats_init && blockIdx.x == 0 && blockIdx.y == 0 && threadIdx.x == 0) {
    stats_init[0] = 0u; stats_init[1] = 0u; stats_init[2] = 0u;  // sumexp,maxkey,counter
  }
  __shared__ float As[32][34];
  __shared__ float Bs[32][34];
  const int t  = threadIdx.x;
  const int rowbase = blockIdx.y * 32;
  const int colbase = blockIdx.x * 32;
  const int sm = t >> 3;
  const int kc = (t & 7) << 2;
  const int ty = t >> 4, tx = t & 15;
  float a00 = 0.f, a01 = 0.f, a10 = 0.f, a11 = 0.f;
  for (int kt = 0; kt < KDIM; kt += 32) {
    float4 av = *(const float4*)(A + (size_t)(rowbase + sm) * KDIM + kt + kc);
    float4 bv = *(const float4*)(B + (size_t)(colbase + sm) * KDIM + kt + kc);
    __syncthreads();
    As[kc+0][sm] = av.x; As[kc+1][sm] = av.y; As[kc+2][sm] = av.z; As[kc+3][sm] = av.w;
    Bs[kc+0][sm] = bv.x; Bs[kc+1][sm] = bv.y; Bs[kc+2][sm] = bv.z; Bs[kc+3][sm] = bv.w;
    __syncthreads();
#pragma unroll
    for (int j = 0; j < 32; ++j) {
      float2 a = *(const float2*)(&As[j][2*ty]);
      float2 b = *(const float2*)(&Bs[j][2*tx]);
      a00 = fmaf(a.x, b.x, a00); a01 = fmaf(a.x, b.y, a01);
      a10 = fmaf(a.y, b.x, a10); a11 = fmaf(a.y, b.y, a11);
    }
  }
  const int r0 = rowbase + 2*ty;
  const int c0 = colbase + 2*tx;
  const float bb0 = bias[c0], bb1 = bias[c0+1];
  float v00 = a00 + bb0, v01 = a01 + bb1, v10 = a10 + bb0, v11 = a11 + bb1;
  if (RELU) {
    v00 = fmaxf(v00, 0.f); v01 = fmaxf(v01, 0.f);
    v10 = fmaxf(v10, 0.f); v11 = fmaxf(v11, 0.f);
  }
  C[(size_t)r0*NCOLS + c0]       = v00; C[(size_t)r0*NCOLS + c0 + 1]     = v01;
  C[(size_t)(r0+1)*NCOLS + c0]   = v10; C[(size_t)(r0+1)*NCOLS + c0 + 1] = v11;
}

// ---------------- normalize rows + bf16 cast into [k/8][n][8] layout ----------------
__global__ __launch_bounds__(256) void norm_cast_kernel(const float* __restrict__ img,
    float* __restrict__ img_n, bf16_t* __restrict__ img_t) {
  const int row = blockIdx.x, t = threadIdx.x;
  const float v0 = img[row*DOUT + t];
  const float v1 = img[row*DOUT + 256 + t];
  float s = v0*v0 + v1*v1;
  for (int o = 32; o > 0; o >>= 1) s += __shfl_down(s, o);
  __shared__ float ws4[4];
  if ((t & 63) == 0) ws4[t >> 6] = s;
  __syncthreads();
  const float tot = ws4[0] + ws4[1] + ws4[2] + ws4[3];
  const float inv = 1.0f / sqrtf(tot);
  const float n0 = v0 * inv, n1 = v1 * inv;
  img_n[row*DOUT + t]       = n0;
  img_n[row*DOUT + 256 + t] = n1;
  // transposed bf16 layout: element (n, k) -> img_t[((k>>3)*N_IMG + n)*8 + (k&7)]
  const int k0 = t, k1 = t + 256;
  img_t[(((k0 >> 3)*N_IMG) + row)*8 + (k0 & 7)] = (bf16_t)n0;
  img_t[(((k1 >> 3)*N_IMG) + row)*8 + (k1 & 7)] = (bf16_t)n1;
}

// ---------------- main logits GEMM ----------------
// Block: ALL 256 images x 64 gallery rows (loc single-pass).
// 4 waves; wave = 128 img x 32 gal, mfma_f32_32x32x16_bf16 (acc = 4x f32x16).
// KEY CHANGE vs rounds 0-3: B (loc) no longer streamed per-lane (which made
// every B-load a 32-cache-line scatter-gather, 2x duplicated across waves --
// the real serial resource). B now goes through LDS in the SAME conflict-free
// [k8][row][8] bf16 layout as A: coalesced f32 loads (8 lanes/row) -> cvt ->
// ds_write. Per-kt compute is pure LDS (5x ds_read_b128 + 4 MFMA), zero
// per-kt global dependency. Sync = round-1's proven 2-barrier-per-chunk,
// single-buffered, plain __syncthreads() only.
// LDS 40 KB -> 4 blocks/CU (16 waves/CU).
__global__ __launch_bounds__(256, 4) void logits_kernel(const float* __restrict__ loc,
    const bf16_t* __restrict__ img_t, const float* __restrict__ ls,
    float* __restrict__ out, float* __restrict__ sumexp, unsigned* __restrict__ maxkey) {
  __shared__ bf16_t Asl[8 * 256 * 8];   // 32 KB: [k8 0..7][img 0..255][8]
  __shared__ bf16_t Bsl[8 * 64 * 8];    //  8 KB: [k8 0..7][row 0..63][8]
  const int t = threadIdx.x;
  const int w = t >> 6, l = t & 63;
  const int wr = w >> 1;        // img half: 0 -> imgs 0..127, 1 -> 128..255
  const int wc = w & 1;         // gal half: 0 -> gals +0..31, 1 -> +32..63
  const int hi = l >> 5;        // k-subgroup within K=16 (0: k0..7, 1: k8..15)
  const int lo = l & 31;
  const int mb = blockIdx.x * 64;
  const int m  = mb + wc * 32 + lo;              // this lane's gallery row (output)

  // ---- B staging map: thread t owns cells (k8 = t&7, rows t>>3 and 32+(t>>3)) ----
  // Global side: per wave, 8 lanes share one row (32B stride) -> coalesced.
  // LDS side: [k8][row][8] -> 16B/lane stride on reads = conflict-free.
  const int sk8 = t & 7, sr0 = t >> 3;
  const int gr0 = min(mb + sr0,      M_GAL - 1);
  const int gr1 = min(mb + 32 + sr0, M_GAL - 1);
  const float* sp0 = loc + (size_t)gr0 * 512 + sk8 * 8;
  const float* sp1 = loc + (size_t)gr1 * 512 + sk8 * 8;
  bf16_t* bw0 = Bsl + (sk8 * 64 + sr0) * 8;
  bf16_t* bw1 = bw0 + 32 * 8;

  f32x16 acc[4];
#pragma unroll
  for (int i = 0; i < 4; ++i) acc[i] = (f32x16)(0.f);

  float4 r00, r01, r10, r11;   // B staging registers (next chunk, raw f32)

#define BLOAD(c_) {                                                   \
    const float* p0_ = sp0 + (c_) * 64;                               \
    const float* p1_ = sp1 + (c_) * 64;                               \
    r00 = *(const float4*)p0_; r01 = *(const float4*)(p0_ + 4);       \
    r10 = *(const float4*)p1_; r11 = *(const float4*)(p1_ + 4);       \
  }

#define BWRITE() {                                                    \
    bf16x8 b0_, b1_;                                                  \
    b0_[0] = (bf16_t)r00.x; b0_[1] = (bf16_t)r00.y;                   \
    b0_[2] = (bf16_t)r00.z; b0_[3] = (bf16_t)r00.w;                   \
    b0_[4] = (bf16_t)r01.x; b0_[5] = (bf16_t)r01.y;                   \
    b0_[6] = (bf16_t)r01.z; b0_[7] = (bf16_t)r01.w;                   \
    b1_[0] = (bf16_t)r10.x; b1_[1] = (bf16_t)r10.y;                   \
    b1_[2] = (bf16_t)r10.z; b1_[3] = (bf16_t)r10.w;                   \
    b1_[4] = (bf16_t)r11.x; b1_[5] = (bf16_t)r11.y;                   \
    b1_[6] = (bf16_t)r11.z; b1_[7] = (bf16_t)r11.w;                   \
    *(bf16x8*)bw0 = b0_;                                              \
    *(bf16x8*)bw1 = b1_;                                              \
  }

  // stage A chunk c: 8 rounds x (256 threads x 16 B) = 32 KB, linear in t
#define STAGEA(c_) {                                                  \
    _Pragma("unroll")                                                 \
    for (int r_ = 0; r_ < 8; ++r_) {                                  \
      __builtin_amdgcn_global_load_lds(                               \
          (__attribute__((address_space(1))) void*)(img_t + (((c_) * 8 + r_) * 256 + t) * 8), \
          (__attribute__((address_space(3))) void*)(Asl + (r_ * 256 + t) * 8), \
          16, 0, 0);                                                  \
    } }

  // per-kt compute: pure LDS reads + 4 MFMA (kt = global K-step of 16)
#define COMPUTE(kt) {                                                 \
    const int kl_ = ((kt) & 3) * 2 + hi;  /* k8 within chunk */       \
    bf16x8 af_[4];                                                    \
    _Pragma("unroll")                                                 \
    for (int i_ = 0; i_ < 4; ++i_)                                    \
      af_[i_] = *(const bf16x8*)(Asl + (kl_ * 256 + wr * 128 + i_ * 32 + lo) * 8); \
    const bf16x8 bf_ = *(const bf16x8*)(Bsl + (kl_ * 64 + wc * 32 + lo) * 8); \
    _Pragma("unroll")                                                 \
    for (int i_ = 0; i_ < 4; ++i_)                                    \
      acc[i_] = __builtin_amdgcn_mfma_f32_32x32x16_bf16(af_[i_], bf_, acc[i_], 0, 0, 0); \
  }

  // ---- prologue: chunk 0 into LDS ----
  BLOAD(0);
  STAGEA(0);
  BWRITE();          // compiler inserts vmcnt wait for r-regs before the cvt
  __syncthreads();   // A stage 0 drained + B writes visible

#pragma unroll
  for (int c = 0; c < 8; ++c) {
    if (c < 7) { BLOAD(c + 1); }   // issue early; lands during this chunk's compute
#pragma unroll
    for (int q = 0; q < 4; ++q) {
      COMPUTE(c * 4 + q);
    }
    if (c < 7) {
      __syncthreads();   // all waves done reading chunk c
      STAGEA(c + 1);
      BWRITE();
      __syncthreads();   // chunk c+1 resident
    }
  }
#undef BLOAD
#undef BWRITE
#undef STAGEA
#undef COMPUTE

  const float scale = expf(ls[0]);
  // ---- row-0 softmax stats folded into epilogue (img 0: wr==0, acc[0] reg 0, hi==0) ----
  if (wr == 0) {
    float mx = -1e30f, se = 0.f;
    if (hi == 0 && m < M_GAL) {
      const float v = scale * acc[0][0];
      mx = v;
      se = expf(v);
    }
#pragma unroll
    for (int o = 1; o < 64; o <<= 1) {
      mx = fmaxf(mx, __shfl_xor(mx, o));
      se += __shfl_xor(se, o);
    }
    if (l == 0) { atomicAdd(sumexp, se); atomicMax(maxkey, fkey(mx)); }
  }
  // ---- store: D col = gallery = lo, row = img = wr*128 + i*32 + (r&3) + 8*(r>>2) + 4*hi ----
  if (m < M_GAL) {
#pragma unroll
    for (int i = 0; i < 4; ++i) {
      const int ib = wr * 128 + i * 32 + hi * 4;
#pragma unroll
      for (int r = 0; r < 16; ++r) {
        const int img = ib + (r & 3) + 8 * (r >> 2);
        out[(size_t)img * M_GAL + m] = scale * acc[i][r];
      }
    }
  }
}

// ---------------- collect candidates within 0.8 of row-0 max ----------------
__global__ __launch_bounds__(256) void collect_kernel(const float* __restrict__ out,
    const unsigned* __restrict__ maxkey, unsigned* __restrict__ counter,
    int* __restrict__ cidx) {
  const int i = blockIdx.x * 256 + threadIdx.x;
  if (i >= M_GAL) return;
  const float thresh = fkey_inv(*maxkey) - 0.8f;
  if (out[i] > thresh) {
    const unsigned p = atomicAdd(counter, 1u);
    if (p < CAP) cidx[p] = i;
  }
}

// ---------------- exact f32 recompute of candidate logits (multi-block) ----------------
__global__ __launch_bounds__(256) void recompute_kernel(const float* __restrict__ loc,
    const float* __restrict__ img_n, const float* __restrict__ ls,
    const unsigned* __restrict__ counter, const int* __restrict__ cidx,
    float* __restrict__ cval) {
  const int w = threadIdx.x >> 6, l = threadIdx.x & 63;
  const unsigned cnt = *counter;
  const int n = (int)(cnt < CAP ? cnt : CAP);
  const float scale = expf(ls[0]);
  for (int c = blockIdx.x * 4 + w; c < n; c += gridDim.x * 4) {
    const int idx = cidx[c];
    const float* B = loc + (size_t)idx * 512;
    float s = 0.f;
#pragma unroll
    for (int e = 0; e < 8; ++e) s = fmaf(img_n[l + e*64], B[l + e*64], s);
    for (int o = 32; o > 0; o >>= 1) s += __shfl_down(s, o);
    if (l == 0) cval[c] = scale * s;
  }
}

// ---------------- exact top-5 among candidates + outputs ----------------
__global__ __launch_bounds__(256) void finalize_kernel(const unsigned* __restrict__ counter,
    const int* __restrict__ cidx, const float* __restrict__ cval,
    const float* __restrict__ gps, const float* __restrict__ sumexp,
    float* __restrict__ out) {
  __shared__ float v[CAP];
  __shared__ int   id[CAP];
  __shared__ float rv[256];
  __shared__ int   ri[256];
  __shared__ int   rs[256];
  const int t = threadIdx.x;
  const unsigned cnt = *counter;
  const int n = (int)(cnt < CAP ? cnt : CAP);
  for (int i = t; i < CAP; i += 256) {
    v[i]  = (i < n) ? cval[i] : -1e30f;
    id[i] = (i < n) ? cidx[i] : 0x7fffffff;
  }
  const float se = *sumexp;
  __syncthreads();
  for (int k = 0; k < 5; ++k) {
    float bv = -1e30f; int bidx = 0x7fffffff; int bslot = -1;
    for (int i = t; i < CAP; i += 256) {
      const float vi = v[i]; const int ii = id[i];
      if (vi > bv || (vi == bv && ii < bidx)) { bv = vi; bidx = ii; bslot = i; }
    }
    rv[t] = bv; ri[t] = bidx; rs[t] = bslot;
    __syncthreads();
    for (int s = 128; s > 0; s >>= 1) {
      if (t < s) {
        if (rv[t+s] > rv[t] || (rv[t+s] == rv[t] && ri[t+s] < ri[t])) {
          rv[t] = rv[t+s]; ri[t] = ri[t+s]; rs[t] = rs[t+s];
        }
      }
      __syncthreads();
    }
    if (t == 0) {
      const int sl = rs[0]; const int gi = ri[0]; const float lv = rv[0];
      float g0 = 0.f, g1 = 0.f, pr = 0.f;
      if (sl >= 0 && gi != 0x7fffffff) {
        g0 = gps[(size_t)gi*2]; g1 = gps[(size_t)gi*2 + 1];
        pr = expf(lv) / se;
        v[sl] = -1e30f; id[sl] = 0x7fffffff;
      }
      out[OUT_GPS + 2*k]     = g0;
      out[OUT_GPS + 2*k + 1] = g1;
      out[OUT_PROB + k]      = pr;
    }
    __syncthreads();
  }
}

extern "C" void kernel_launch(void* const* d_in, const int* in_sizes, int n_in,
                              void* d_out, int out_size, void* d_ws, size_t ws_size,
                              hipStream_t stream) {
  const float* img_feats = (const float*)d_in[0];
  const float* w1  = (const float*)d_in[1];
  const float* b1  = (const float*)d_in[2];
  const float* w2  = (const float*)d_in[3];
  const float* b2  = (const float*)d_in[4];
  const float* ls  = (const float*)d_in[5];
  const float* loc = (const float*)d_in[6];
  const float* gps = (const float*)d_in[7];
  float* out = (float*)d_out;
  float* ws  = (float*)d_ws;

  float*    h       = ws + OFF_H;
  float*    img     = ws + OFF_IMG;
  float*    img_n   = ws + OFF_IMGN;
  bf16_t*   img_t   = (bf16_t*)(ws + OFF_IMGT);
  float*    sumexp  = ws + OFF_STATS;
  unsigned* maxkey  = (unsigned*)(ws + OFF_STATS + 1);
  unsigned* counter = (unsigned*)(ws + OFF_STATS + 2);
  int*      cidx    = (int*)(ws + OFF_CIDX);
  float*    cval    = ws + OFF_CVAL;

  // 1-2: MLP head (f32 exact); first launch also zeroes the stats words
  mlp_gemm<DIN, DH, true><<<dim3(DH/32, N_IMG/32), 256, 0, stream>>>(
      img_feats, w1, b1, h, (unsigned*)(ws + OFF_STATS));
  mlp_gemm<DH, DOUT, false><<<dim3(DOUT/32, N_IMG/32), 256, 0, stream>>>(
      h, w2, b2, img, nullptr);
  // 3: normalize + bf16 transpose-cast
  norm_cast_kernel<<<N_IMG, 256, 0, stream>>>(img, img_n, img_t);
  // 4: streaming logits GEMM (+ row-0 stats folded into epilogue)
  logits_kernel<<<MT, 256, 0, stream>>>(loc, img_t, ls, out, sumexp, maxkey);
  // 5: candidate collection (row 0 only: 400 KB)
  collect_kernel<<<(M_GAL + 255) / 256, 256, 0, stream>>>(out, maxkey, counter, cidx);
  // 6-7: exact f32 recompute (multi-block) + top-5 + gps/prob outputs
  recompute_kernel<<<128, 256, 0, stream>>>(loc, img_n, ls, counter, cidx, cval);
  finalize_kernel<<<1, 256, 0, stream>>>(counter, cidx, cval, gps, sumexp, out);
}

// Round 6
// 428.990 us; speedup vs baseline: 1.1203x; 1.0305x over previous
//
#include <hip/hip_runtime.h>
#include <math.h>

#define N_IMG 256
#define DIN   768
#define DH    768
#define DOUT  512
#define M_GAL 100000
#define CAP   2048
#define MT    1568  // m-tiles of 64 gallery rows (1568*64 = 100352 >= 100000)

typedef __bf16 bf16_t;
typedef __bf16 bf16x8 __attribute__((ext_vector_type(8)));
typedef float  f32x4  __attribute__((ext_vector_type(4)));
typedef float  f32x16 __attribute__((ext_vector_type(16)));

// ---- workspace layout (float units) ----
#define OFF_H      0                               // 256*768
#define OFF_IMG    (N_IMG*DH)                      // 256*512 pre-norm
#define OFF_IMGN   (OFF_IMG  + N_IMG*DOUT)         // 256*512 f32 normalized
#define OFF_IMGT   (OFF_IMGN + N_IMG*DOUT)         // 256*512 bf16, [k/8][n][8] layout
#define OFF_STATS  (OFF_IMGT + N_IMG*DOUT/2)       // [0]=sumexp [1]=maxkey [2]=counter
#define OFF_CIDX   (OFF_STATS + 4)
#define OFF_CVAL   (OFF_CIDX + CAP)

#define OUT_GPS  ((size_t)N_IMG * (size_t)M_GAL)
#define OUT_PROB (OUT_GPS + 10)

__device__ inline unsigned fkey(float x) {
  unsigned u = __float_as_uint(x);
  return (u & 0x80000000u) ? ~u : (u | 0x80000000u);
}
__device__ inline float fkey_inv(unsigned k) {
  unsigned u = (k & 0x80000000u) ? (k ^ 0x80000000u) : ~k;
  return __uint_as_float(u);
}

// ---------------- MLP GEMM (f32 VALU, 32x32 tile, 2x2 micro) ----------------
template<int KDIM, int NCOLS, bool RELU>
__global__ __launch_bounds__(256) void mlp_gemm(const float* __restrict__ A,
    const float* __restrict__ B, const float* __restrict__ bias,
    float* __restrict__ C, unsigned* stats_init) {
  if (stats_init && blockIdx.x == 0 && blockIdx.y == 0 && threadIdx.x == 0) {
    stats_init[0] = 0u; stats_init[1] = 0u; stats_init[2] = 0u;  // sumexp,maxkey,counter
  }
  __shared__ float As[32][34];
  __shared__ float Bs[32][34];
  const int t  = threadIdx.x;
  const int rowbase = blockIdx.y * 32;
  const int colbase = blockIdx.x * 32;
  const int sm = t >> 3;
  const int kc = (t & 7) << 2;
  const int ty = t >> 4, tx = t & 15;
  float a00 = 0.f, a01 = 0.f, a10 = 0.f, a11 = 0.f;
  for (int kt = 0; kt < KDIM; kt += 32) {
    float4 av = *(const float4*)(A + (size_t)(rowbase + sm) * KDIM + kt + kc);
    float4 bv = *(const float4*)(B + (size_t)(colbase + sm) * KDIM + kt + kc);
    __syncthreads();
    As[kc+0][sm] = av.x; As[kc+1][sm] = av.y; As[kc+2][sm] = av.z; As[kc+3][sm] = av.w;
    Bs[kc+0][sm] = bv.x; Bs[kc+1][sm] = bv.y; Bs[kc+2][sm] = bv.z; Bs[kc+3][sm] = bv.w;
    __syncthreads();
#pragma unroll
    for (int j = 0; j < 32; ++j) {
      float2 a = *(const float2*)(&As[j][2*ty]);
      float2 b = *(const float2*)(&Bs[j][2*tx]);
      a00 = fmaf(a.x, b.x, a00); a01 = fmaf(a.x, b.y, a01);
      a10 = fmaf(a.y, b.x, a10); a11 = fmaf(a.y, b.y, a11);
    }
  }
  const int r0 = rowbase + 2*ty;
  const int c0 = colbase + 2*tx;
  const float bb0 = bias[c0], bb1 = bias[c0+1];
  float v00 = a00 + bb0, v01 = a01 + bb1, v10 = a10 + bb0, v11 = a11 + bb1;
  if (RELU) {
    v00 = fmaxf(v00, 0.f); v01 = fmaxf(v01, 0.f);
    v10 = fmaxf(v10, 0.f); v11 = fmaxf(v11, 0.f);
  }
  C[(size_t)r0*NCOLS + c0]       = v00; C[(size_t)r0*NCOLS + c0 + 1]     = v01;
  C[(size_t)(r0+1)*NCOLS + c0]   = v10; C[(size_t)(r0+1)*NCOLS + c0 + 1] = v11;
}

// ---------------- normalize rows + bf16 cast into [k/8][n][8] layout ----------------
__global__ __launch_bounds__(256) void norm_cast_kernel(const float* __restrict__ img,
    float* __restrict__ img_n, bf16_t* __restrict__ img_t) {
  const int row = blockIdx.x, t = threadIdx.x;
  const float v0 = img[row*DOUT + t];
  const float v1 = img[row*DOUT + 256 + t];
  float s = v0*v0 + v1*v1;
  for (int o = 32; o > 0; o >>= 1) s += __shfl_down(s, o);
  __shared__ float ws4[4];
  if ((t & 63) == 0) ws4[t >> 6] = s;
  __syncthreads();
  const float tot = ws4[0] + ws4[1] + ws4[2] + ws4[3];
  const float inv = 1.0f / sqrtf(tot);
  const float n0 = v0 * inv, n1 = v1 * inv;
  img_n[row*DOUT + t]       = n0;
  img_n[row*DOUT + 256 + t] = n1;
  // transposed bf16 layout: element (n, k) -> img_t[((k>>3)*N_IMG + n)*8 + (k&7)]
  const int k0 = t, k1 = t + 256;
  img_t[(((k0 >> 3)*N_IMG) + row)*8 + (k0 & 7)] = (bf16_t)n0;
  img_t[(((k1 >> 3)*N_IMG) + row)*8 + (k1 & 7)] = (bf16_t)n1;
}

// ---------------- main logits GEMM ----------------
// OCCUPANCY round, conservative mechanics: identical launch shape to the
// PASSING round-4 kernel (256 threads / 4 waves, plain __syncthreads, same
// 2-barrier-per-chunk template). Occupancy comes from a smaller block tile:
//   block = 128 img x 64 gal, wave = 64 img x 32 gal -> acc = 2x f32x16.
//   LDS = 16 KB (A: [k8][img 0..127][8]) + 8 KB (B) = 24 KB.
//   __launch_bounds__(256,5) -> 5 blocks/CU = 20 waves/CU (~62%) vs 11.
// loc single-fetch preserved: the two img-half blocks of an m-tile are 8
// apart in blockIdx (same XCD under %8 round-robin) -> pair-mate's B panel
// L2-hits. B ds_write 8-way bank conflict from round 4 fixed by XOR row
// swizzle (row^k8) applied on BOTH write and read (bijective within 64 rows).
__global__ __launch_bounds__(256, 5) void logits_kernel(const float* __restrict__ loc,
    const bf16_t* __restrict__ img_t, const float* __restrict__ ls,
    float* __restrict__ out, float* __restrict__ sumexp, unsigned* __restrict__ maxkey) {
  __shared__ bf16_t Asl[8 * 128 * 8];   // 16 KB: [k8 0..7][img 0..127][8]
  __shared__ bf16_t Bsl[8 * 64 * 8];    //  8 KB: [k8 0..7][row^k8][8]
  const int t = threadIdx.x;
  const int w = t >> 6, l = t & 63;
  const int wi = w >> 1;        // img half within block's 128: 0 -> 0..63, 1 -> 64..127
  const int wc = w & 1;         // gal half: 0 -> gals +0..31, 1 -> +32..63
  const int hi = l >> 5;        // k-subgroup within K=16 (0: k0..7, 1: k8..15)
  const int lo = l & 31;
  const int bx = blockIdx.x;
  // pair the two img-halves of an m-tile 8 blocks apart (same XCD, adjacent
  // in dispatch) so the second one L2-hits the same loc panel.
  const int mtile = (bx & 7) + (bx >> 4) * 8;    // 0..1567
  const int h     = (bx >> 3) & 1;               // img half: 0 -> 0..127, 1 -> 128..255
  const int mb = mtile * 64;
  const int m  = mb + wc * 32 + lo;              // this lane's gallery row (output)

  // ---- B staging map: thread t owns cells (k8 = t&7, rows t>>3 and 32+(t>>3)) ----
  // Global: 8 lanes cover one loc row's 64-float chunk-column (256B) -> coalesced.
  // LDS: [k8][row ^ k8][8] -> conflict-free b128 writes AND reads.
  const int sk8 = t & 7, sr0 = t >> 3;           // sr0 0..31
  const int gr0 = min(mb + sr0,      M_GAL - 1);
  const int gr1 = min(mb + 32 + sr0, M_GAL - 1);
  const float* sp0 = loc + (size_t)gr0 * 512 + sk8 * 8;
  const float* sp1 = loc + (size_t)gr1 * 512 + sk8 * 8;
  // (sr0+32)^sk8 == (sr0^sk8)+32 since sk8<8, so bw1 = bw0 + 32*8.
  bf16_t* bw0 = Bsl + (sk8 * 64 + (sr0 ^ sk8)) * 8;
  bf16_t* bw1 = bw0 + 32 * 8;

  f32x16 acc[2];
  acc[0] = (f32x16)(0.f);
  acc[1] = (f32x16)(0.f);

  float4 r00, r01, r10, r11;   // B staging registers (next chunk, raw f32)

#define BLOAD(c_) {                                                   \
    const float* p0_ = sp0 + (c_) * 64;                               \
    const float* p1_ = sp1 + (c_) * 64;                               \
    r00 = *(const float4*)p0_; r01 = *(const float4*)(p0_ + 4);       \
    r10 = *(const float4*)p1_; r11 = *(const float4*)(p1_ + 4);       \
  }

#define BWRITE() {                                                    \
    bf16x8 b0_, b1_;                                                  \
    b0_[0] = (bf16_t)r00.x; b0_[1] = (bf16_t)r00.y;                   \
    b0_[2] = (bf16_t)r00.z; b0_[3] = (bf16_t)r00.w;                   \
    b0_[4] = (bf16_t)r01.x; b0_[5] = (bf16_t)r01.y;                   \
    b0_[6] = (bf16_t)r01.z; b0_[7] = (bf16_t)r01.w;                   \
    b1_[0] = (bf16_t)r10.x; b1_[1] = (bf16_t)r10.y;                   \
    b1_[2] = (bf16_t)r10.z; b1_[3] = (bf16_t)r10.w;                   \
    b1_[4] = (bf16_t)r11.x; b1_[5] = (bf16_t)r11.y;                   \
    b1_[6] = (bf16_t)r11.z; b1_[7] = (bf16_t)r11.w;                   \
    *(bf16x8*)bw0 = b0_;                                              \
    *(bf16x8*)bw1 = b1_;                                              \
  }

  // stage A chunk c (img half h): 4 rounds x (256 threads x 16 B) = 16 KB.
  // LDS offset (r_*256+t)*8 == ((r_*2 + (t>>7))*128 + (t&127))*8 -> [k8l][img][8].
#define STAGEA(c_) {                                                  \
    _Pragma("unroll")                                                 \
    for (int r_ = 0; r_ < 4; ++r_) {                                  \
      __builtin_amdgcn_global_load_lds(                               \
          (__attribute__((address_space(1))) void*)(img_t + (((size_t)((c_) * 8 + r_ * 2 + (t >> 7)) * 256 + h * 128 + (t & 127))) * 8), \
          (__attribute__((address_space(3))) void*)(Asl + (r_ * 256 + t) * 8), \
          16, 0, 0);                                                  \
    } }

  // per-kt compute: pure LDS reads + 2 MFMA (kt = global K-step of 16)
#define COMPUTE(kt) {                                                 \
    const int kl_ = ((kt) & 3) * 2 + hi;  /* k8 within chunk, 0..7 */ \
    bf16x8 af_[2];                                                    \
    _Pragma("unroll")                                                 \
    for (int i_ = 0; i_ < 2; ++i_)                                    \
      af_[i_] = *(const bf16x8*)(Asl + (kl_ * 128 + wi * 64 + i_ * 32 + lo) * 8); \
    const bf16x8 bf_ = *(const bf16x8*)(Bsl + (kl_ * 64 + ((wc * 32 + lo) ^ kl_)) * 8); \
    _Pragma("unroll")                                                 \
    for (int i_ = 0; i_ < 2; ++i_)                                    \
      acc[i_] = __builtin_amdgcn_mfma_f32_32x32x16_bf16(af_[i_], bf_, acc[i_], 0, 0, 0); \
  }

  // ---- prologue: chunk 0 into LDS ----
  BLOAD(0);
  STAGEA(0);
  BWRITE();          // compiler inserts vmcnt wait for r-regs before the cvt
  __syncthreads();   // A stage 0 drained + B writes visible

#pragma unroll
  for (int c = 0; c < 8; ++c) {
    if (c < 7) { BLOAD(c + 1); }   // issue early; lands during this chunk's compute
#pragma unroll
    for (int q = 0; q < 4; ++q) {
      COMPUTE(c * 4 + q);
    }
    if (c < 7) {
      __syncthreads();   // all waves done reading chunk c
      STAGEA(c + 1);
      BWRITE();
      __syncthreads();   // chunk c+1 resident
    }
  }
#undef BLOAD
#undef BWRITE
#undef STAGEA
#undef COMPUTE

  const float scale = expf(ls[0]);
  // ---- row-0 softmax stats folded into epilogue ----
  // img 0 lives only in h==0 blocks, waves with wi==0 (w=0,1), acc[0] reg 0, hi==0.
  if (h == 0 && wi == 0) {
    float mx = -1e30f, se = 0.f;
    if (hi == 0 && m < M_GAL) {
      const float v = scale * acc[0][0];
      mx = v;
      se = expf(v);
    }
#pragma unroll
    for (int o = 1; o < 64; o <<= 1) {
      mx = fmaxf(mx, __shfl_xor(mx, o));
      se += __shfl_xor(se, o);
    }
    if (l == 0) { atomicAdd(sumexp, se); atomicMax(maxkey, fkey(mx)); }
  }
  // ---- store: col = gallery = m, row = img = h*128 + wi*64 + i*32 + (r&3)+8*(r>>2)+4*hi ----
  if (m < M_GAL) {
#pragma unroll
    for (int i = 0; i < 2; ++i) {
      const int ib = h * 128 + wi * 64 + i * 32 + hi * 4;
#pragma unroll
      for (int r = 0; r < 16; ++r) {
        const int img = ib + (r & 3) + 8 * (r >> 2);
        out[(size_t)img * M_GAL + m] = scale * acc[i][r];
      }
    }
  }
}

// ---------------- collect candidates within 0.8 of row-0 max ----------------
__global__ __launch_bounds__(256) void collect_kernel(const float* __restrict__ out,
    const unsigned* __restrict__ maxkey, unsigned* __restrict__ counter,
    int* __restrict__ cidx) {
  const int i = blockIdx.x * 256 + threadIdx.x;
  if (i >= M_GAL) return;
  const float thresh = fkey_inv(*maxkey) - 0.8f;
  if (out[i] > thresh) {
    const unsigned p = atomicAdd(counter, 1u);
    if (p < CAP) cidx[p] = i;
  }
}

// ---------------- exact f32 recompute of candidate logits (multi-block) ----------------
__global__ __launch_bounds__(256) void recompute_kernel(const float* __restrict__ loc,
    const float* __restrict__ img_n, const float* __restrict__ ls,
    const unsigned* __restrict__ counter, const int* __restrict__ cidx,
    float* __restrict__ cval) {
  const int w = threadIdx.x >> 6, l = threadIdx.x & 63;
  const unsigned cnt = *counter;
  const int n = (int)(cnt < CAP ? cnt : CAP);
  const float scale = expf(ls[0]);
  for (int c = blockIdx.x * 4 + w; c < n; c += gridDim.x * 4) {
    const int idx = cidx[c];
    const float* B = loc + (size_t)idx * 512;
    float s = 0.f;
#pragma unroll
    for (int e = 0; e < 8; ++e) s = fmaf(img_n[l + e*64], B[l + e*64], s);
    for (int o = 32; o > 0; o >>= 1) s += __shfl_down(s, o);
    if (l == 0) cval[c] = scale * s;
  }
}

// ---------------- exact top-5 among candidates + outputs ----------------
__global__ __launch_bounds__(256) void finalize_kernel(const unsigned* __restrict__ counter,
    const int* __restrict__ cidx, const float* __restrict__ cval,
    const float* __restrict__ gps, const float* __restrict__ sumexp,
    float* __restrict__ out) {
  __shared__ float v[CAP];
  __shared__ int   id[CAP];
  __shared__ float rv[256];
  __shared__ int   ri[256];
  __shared__ int   rs[256];
  const int t = threadIdx.x;
  const unsigned cnt = *counter;
  const int n = (int)(cnt < CAP ? cnt : CAP);
  for (int i = t; i < CAP; i += 256) {
    v[i]  = (i < n) ? cval[i] : -1e30f;
    id[i] = (i < n) ? cidx[i] : 0x7fffffff;
  }
  const float se = *sumexp;
  __syncthreads();
  for (int k = 0; k < 5; ++k) {
    float bv = -1e30f; int bidx = 0x7fffffff; int bslot = -1;
    for (int i = t; i < CAP; i += 256) {
      const float vi = v[i]; const int ii = id[i];
      if (vi > bv || (vi == bv && ii < bidx)) { bv = vi; bidx = ii; bslot = i; }
    }
    rv[t] = bv; ri[t] = bidx; rs[t] = bslot;
    __syncthreads();
    for (int s = 128; s > 0; s >>= 1) {
      if (t < s) {
        if (rv[t+s] > rv[t] || (rv[t+s] == rv[t] && ri[t+s] < ri[t])) {
          rv[t] = rv[t+s]; ri[t] = ri[t+s]; rs[t] = rs[t+s];
        }
      }
      __syncthreads();
    }
    if (t == 0) {
      const int sl = rs[0]; const int gi = ri[0]; const float lv = rv[0];
      float g0 = 0.f, g1 = 0.f, pr = 0.f;
      if (sl >= 0 && gi != 0x7fffffff) {
        g0 = gps[(size_t)gi*2]; g1 = gps[(size_t)gi*2 + 1];
        pr = expf(lv) / se;
        v[sl] = -1e30f; id[sl] = 0x7fffffff;
      }
      out[OUT_GPS + 2*k]     = g0;
      out[OUT_GPS + 2*k + 1] = g1;
      out[OUT_PROB + k]      = pr;
    }
    __syncthreads();
  }
}

extern "C" void kernel_launch(void* const* d_in, const int* in_sizes, int n_in,
                              void* d_out, int out_size, void* d_ws, size_t ws_size,
                              hipStream_t stream) {
  const float* img_feats = (const float*)d_in[0];
  const float* w1  = (const float*)d_in[1];
  const float* b1  = (const float*)d_in[2];
  const float* w2  = (const float*)d_in[3];
  const float* b2  = (const float*)d_in[4];
  const float* ls  = (const float*)d_in[5];
  const float* loc = (const float*)d_in[6];
  const float* gps = (const float*)d_in[7];
  float* out = (float*)d_out;
  float* ws  = (float*)d_ws;

  float*    h       = ws + OFF_H;
  float*    img     = ws + OFF_IMG;
  float*    img_n   = ws + OFF_IMGN;
  bf16_t*   img_t   = (bf16_t*)(ws + OFF_IMGT);
  float*    sumexp  = ws + OFF_STATS;
  unsigned* maxkey  = (unsigned*)(ws + OFF_STATS + 1);
  unsigned* counter = (unsigned*)(ws + OFF_STATS + 2);
  int*      cidx    = (int*)(ws + OFF_CIDX);
  float*    cval    = ws + OFF_CVAL;

  // 1-2: MLP head (f32 exact); first launch also zeroes the stats words
  mlp_gemm<DIN, DH, true><<<dim3(DH/32, N_IMG/32), 256, 0, stream>>>(
      img_feats, w1, b1, h, (unsigned*)(ws + OFF_STATS));
  mlp_gemm<DH, DOUT, false><<<dim3(DOUT/32, N_IMG/32), 256, 0, stream>>>(
      h, w2, b2, img, nullptr);
  // 3: normalize + bf16 transpose-cast
  norm_cast_kernel<<<N_IMG, 256, 0, stream>>>(img, img_n, img_t);
  // 4: streaming logits GEMM, 2 img-half blocks per m-tile (+ row-0 stats)
  logits_kernel<<<MT * 2, 256, 0, stream>>>(loc, img_t, ls, out, sumexp, maxkey);
  // 5: candidate collection (row 0 only: 400 KB)
  collect_kernel<<<(M_GAL + 255) / 256, 256, 0, stream>>>(out, maxkey, counter, cidx);
  // 6-7: exact f32 recompute (multi-block) + top-5 + gps/prob outputs
  recompute_kernel<<<128, 256, 0, stream>>>(loc, img_n, ls, counter, cidx, cval);
  finalize_kernel<<<1, 256, 0, stream>>>(counter, cidx, cval, gps, sumexp, out);
}